// Round 19
// baseline (1053.074 us; speedup 1.0000x reference)
//
#include <hip/hip_runtime.h>
#include <hip/hip_fp16.h>
#include <hip/hip_cooperative_groups.h>

namespace cg = cooperative_groups;

// Symmetric pair-weight recurrent net, T=8192, 8 steps of s = tanh(M s + b).
// M stored as strict upper triangle fp16, row-start 16B-aligned:
//   slot(r,j) = crow(r) + j (j > r), crow(r) % 8 == 0.
// Primary path: ONE cooperative persistent kernel (occupancy-queried grid,
// grid-stride phases, grid.sync between iterations). Fallback on ANY launch
// failure: the proven R14 multi-kernel sequence. Shared device bodies.

constexpr int T     = 8192;
constexpr int IN    = 2048;
constexpr int OUT   = 1024;
constexpr int NPROP = 8;

constexpr int TILE   = 128;
constexpr int NT     = T / TILE;              // 64
constexpr int NTILES = NT * (NT + 1) / 2;     // 2080

// f32 source triangle index (j > r)
__device__ __forceinline__ unsigned triidx(unsigned r, unsigned j) {
    return r * (unsigned)(T - 1) - ((r * (r - 1u)) >> 1) + j - r - 1u;
}

// fp16 padded-triangle row base (halves), 16B-aligned slots.
// Max touched slot = crow(8191)+8191 = 33587199 (allocation covers it).
// Write set {crow(r)+j : j>r} injective across rows; sub-diagonal slots
// alias other rows' data (read-only + masked in sym, NEVER stored).
__device__ __forceinline__ int crow(int r) {
    int q = r >> 3, rem = r & 7;
    return r * T - 8 * (4 * q * (q - 1) + q * (rem + 1));
}
constexpr size_t W16_ALLOC = 33587200;        // slots; %8==0

__host__ __device__ __forceinline__ unsigned rowstart(int b) {
    return (unsigned)(b * NT) - (unsigned)((b * (b - 1)) >> 1);
}

__device__ __forceinline__ void tile_decode(unsigned p, int& bi, int& bj) {
    const float A = (float)(2 * NT + 1);      // 129
    bi = (int)((A - sqrtf(A * A - 8.0f * (float)p)) * 0.5f);
    if (bi < 0) bi = 0;
    while (rowstart(bi + 1) <= p) ++bi;
    while (rowstart(bi) > p) --bi;
    bj = bi + (int)(p - rowstart(bi));
}

__device__ __forceinline__ uint4 pack8(const float* v) {
    uint4 pk;
    ushort* us = (ushort*)&pk;
    #pragma unroll
    for (int d = 0; d < 8; ++d) us[d] = __half_as_ushort(__float2half_rn(v[d]));
    return pk;
}

__device__ __forceinline__ void sel8(float4 fA, float4 fB, float4 fC, int sel,
                                     float* v) {
    if (sel == 0) {
        v[0]=fA.x; v[1]=fA.y; v[2]=fA.z; v[3]=fA.w;
        v[4]=fB.x; v[5]=fB.y; v[6]=fB.z; v[7]=fB.w;
    } else if (sel == 1) {
        v[0]=fA.y; v[1]=fA.z; v[2]=fA.w; v[3]=fB.x;
        v[4]=fB.y; v[5]=fB.z; v[6]=fB.w; v[7]=fC.x;
    } else if (sel == 2) {
        v[0]=fA.z; v[1]=fA.w; v[2]=fB.x; v[3]=fB.y;
        v[4]=fB.z; v[5]=fB.w; v[6]=fC.x; v[7]=fC.y;
    } else {
        v[0]=fA.w; v[1]=fB.x; v[2]=fB.y; v[3]=fB.z;
        v[4]=fB.w; v[5]=fC.x; v[6]=fC.y; v[7]=fC.z;
    }
}

// ---- conv body (R14): rows pp and T-1-pp, contiguous streaming ----
__device__ __forceinline__ void conv_rows(int pp, const float* __restrict__ w,
                                          __half* __restrict__ w16) {
    int t = threadIdx.x;
    #pragma unroll
    for (int q = 0; q < 2; ++q) {
        int r = (q == 0) ? pp : (T - 1 - pp);
        int j1 = r + 1;
        int jA = (j1 + 7) & ~7;                 // first aligned chunk col
        unsigned offr = triidx((unsigned)r, (unsigned)j1);
        if (t < jA - j1)                        // head (<8 elems)
            w16[crow(r) + j1 + t] = __float2half_rn(w[offr + (unsigned)t]);
        unsigned baseA = offr + (unsigned)(jA - j1);
        int sel = (int)(baseA & 3u);            // uniform per row
        int cr = crow(r);
        for (int j8 = jA + t * 8; j8 + 8 <= T; j8 += 8 * 256) {
            unsigned a0 = (baseA + (unsigned)(j8 - jA)) & ~3u;
            float4 fA = *(const float4*)(w + a0);
            float4 fB = *(const float4*)(w + a0 + 4);
            float4 fC = *(const float4*)(w + a0 + 8);
            float v[8];
            sel8(fA, fB, fC, sel, v);
            *(uint4*)(w16 + (cr + j8)) = pack8(v);
        }
    }
}

// ---- fused symmetric tile pass (R14 body) ----
// mode 0: full. mode 1: iter1 (bi<16; row side live only bj<16).
// mode 2: iter8 (only y[7168..] live).
// State: sp ? sp[idx] : tanh(yprev[idx] + bv[idx]).
__device__ void sym_tile(unsigned p, const __half* __restrict__ w16,
                         const float* __restrict__ sp,
                         const float* __restrict__ yprev,
                         const float* __restrict__ bv,
                         float* __restrict__ y, int mode) {
    __shared__ float sIl[TILE], sJl[TILE];
    __shared__ float colpart[4][TILE];

    int bi, bj; tile_decode(p, bi, bj);
    if (mode == 2 && bj < (T - OUT) / TILE) return;    // uniform early-out
    bool doRow = (mode == 0) ? true
               : (mode == 1) ? (bj < IN / TILE)
                             : (bi >= (T - OUT) / TILE);

    int i0 = bi * TILE, j0 = bj * TILE;
    int t = threadIdx.x;
    {
        int idx = (t < TILE) ? (i0 + t) : (j0 + (t - TILE));
        float sval = sp ? sp[idx] : tanhf(yprev[idx] + bv[idx]);
        if (t < TILE) sIl[t] = sval;
        else          sJl[t - TILE] = sval;
    }
    __syncthreads();

    int l = t & 63, wv = t >> 6;
    int g = l & 15, ro = l >> 4;
    int cbase = j0 + g * 8;

    float sjv[8];
    #pragma unroll
    for (int d = 0; d < 8; ++d) sjv[d] = sJl[g * 8 + d];
    float colacc[8] = {0.f, 0.f, 0.f, 0.f, 0.f, 0.f, 0.f, 0.f};

    #pragma unroll
    for (int k = 0; k < 8; ++k) {
        int rr = wv * 32 + k * 4 + ro;
        int r  = i0 + rr;
        uint4 wq = *(const uint4*)(w16 + (crow(r) + cbase));
        const __half2* h2 = (const __half2*)&wq;
        float2 f0 = __half22float2(h2[0]);
        float2 f1 = __half22float2(h2[1]);
        float2 f2 = __half22float2(h2[2]);
        float2 f3 = __half22float2(h2[3]);
        float wf[8] = {f0.x, f0.y, f1.x, f1.y, f2.x, f2.y, f3.x, f3.y};

        float si = sIl[rr];
        float rp = 0.0f;
        #pragma unroll
        for (int d = 0; d < 8; ++d) {
            float we = (cbase + d > r) ? wf[d] : 0.0f;   // strict upper only
            colacc[d] = fmaf(we, si, colacc[d]);
            rp        = fmaf(we, sjv[d], rp);
        }
        if (doRow) {
            rp += __shfl_xor(rp, 1, 64);
            rp += __shfl_xor(rp, 2, 64);
            rp += __shfl_xor(rp, 4, 64);
            rp += __shfl_xor(rp, 8, 64);
            if (g == 0) atomicAdd(&y[r], rp);
        }
    }

    #pragma unroll
    for (int d = 0; d < 8; ++d) {
        colacc[d] += __shfl_xor(colacc[d], 16, 64);
        colacc[d] += __shfl_xor(colacc[d], 32, 64);
    }
    if (l < 16) {
        #pragma unroll
        for (int d = 0; d < 8; ++d) colpart[wv][g * 8 + d] = colacc[d];
    }
    __syncthreads();
    if (t < TILE) {
        float c = colpart[0][t] + colpart[1][t] + colpart[2][t] + colpart[3][t];
        atomicAdd(&y[j0 + t], c);
    }
    __syncthreads();   // safe LDS reuse across sequential tile calls
}

// ================= cooperative single-kernel path =================
__global__ __launch_bounds__(256, 8) void all_kernel(
    const float* __restrict__ w, __half* __restrict__ w16,
    const float* __restrict__ in, const float* __restrict__ bv,
    float* __restrict__ s0, float* __restrict__ y, float* __restrict__ out)
{
    cg::grid_group grid = cg::this_grid();
    int t = threadIdx.x;
    int nb = (int)gridDim.x;
    int gid = (int)blockIdx.x * 256 + t;
    int gstride = nb * 256;

    // phase 0: init + conv
    for (int i = gid; i < NPROP * T; i += gstride) y[i] = 0.0f;
    for (int i = gid; i < T; i += gstride) s0[i] = (i < IN) ? in[i] : 0.0f;
    for (int pp = (int)blockIdx.x; pp < T / 2; pp += nb)
        conv_rows(pp, w, w16);
    grid.sync();

    // iter 1: tiles bi<16 (p < 904); state = s0
    for (unsigned p = blockIdx.x; p < rowstart(IN / TILE); p += (unsigned)nb)
        sym_tile(p, w16, s0, nullptr, nullptr, y, 1);
    grid.sync();

    // iters 2..7
    for (int it = 1; it < NPROP - 1; ++it) {
        for (unsigned p = blockIdx.x; p < NTILES; p += (unsigned)nb)
            sym_tile(p, w16, nullptr, y + (it - 1) * T, bv, y + it * T, 0);
        grid.sync();
    }

    // iter 8: only y[7168..] live
    for (unsigned p = blockIdx.x; p < NTILES; p += (unsigned)nb)
        sym_tile(p, w16, nullptr, y + (NPROP - 2) * T, bv,
                 y + (NPROP - 1) * T, 2);
    grid.sync();

    for (int i = gid; i < OUT; i += gstride)
        out[i] = tanhf(y[(NPROP - 1) * T + (T - OUT) + i] + bv[(T - OUT) + i]);
}

// ================= fallback multi-kernel path (R14) =================
__global__ __launch_bounds__(256) void conv_kernel(const float* __restrict__ w,
                                                   __half* __restrict__ w16) {
    conv_rows((int)blockIdx.x, w, w16);
}

__global__ __launch_bounds__(256) void init_kernel(const float* __restrict__ in,
                                                   float* __restrict__ s0,
                                                   float* __restrict__ y) {
    int n = blockIdx.x * 256 + threadIdx.x;
    if (n < T) s0[n] = (n < IN) ? in[n] : 0.0f;
    if (n < NPROP * T) y[n] = 0.0f;
}

__global__ __launch_bounds__(256) void sym_kernel(const __half* __restrict__ w16,
                                                  const float* __restrict__ sp,
                                                  const float* __restrict__ yprev,
                                                  const float* __restrict__ bv,
                                                  float* __restrict__ y, int mode) {
    sym_tile(blockIdx.x, w16, sp, yprev, bv, y, mode);
}

__global__ __launch_bounds__(256) void actout_kernel(const float* __restrict__ b,
                                                     const float* __restrict__ y,
                                                     float* __restrict__ o) {
    int n = blockIdx.x * 256 + threadIdx.x;
    if (n < OUT) o[n] = tanhf(y[T - OUT + n] + b[T - OUT + n]);
}

extern "C" void kernel_launch(void* const* d_in, const int* in_sizes, int n_in,
                              void* d_out, int out_size, void* d_ws, size_t ws_size,
                              hipStream_t stream) {
    const float* in = (const float*)d_in[0];   // inputs [2048]
    const float* w  = (const float*)d_in[1];   // w_flat [T*(T-1)/2] f32
    const float* bv = (const float*)d_in[2];   // b [8192] f32
    float* out = (float*)d_out;                // [1024] f32

    __half* w16 = (__half*)d_ws;                               // 67.17 MB + pad
    float*  s0  = (float*)((char*)d_ws + W16_ALLOC * sizeof(__half));
    float*  y   = s0 + T;                      // 8 accumulators, y + it*T

    // Occupancy-derived cooperative grid (pure host queries, capture-safe).
    hipError_t e = hipErrorUnknown;
    int dev = 0, numCU = 0, maxB = 0;
    if (hipGetDevice(&dev) == hipSuccess &&
        hipDeviceGetAttribute(&numCU, hipDeviceAttributeMultiprocessorCount,
                              dev) == hipSuccess &&
        hipOccupancyMaxActiveBlocksPerMultiprocessor(
            &maxB, (const void*)all_kernel, 256, 0) == hipSuccess &&
        maxB > 0 && numCU > 0) {
        int nblk = maxB * numCU;
        if (nblk > 2048) nblk = 2048;
        if (nblk >= 256) {
            void* args[] = {(void*)&w, (void*)&w16, (void*)&in, (void*)&bv,
                            (void*)&s0, (void*)&y, (void*)&out};
            e = hipLaunchCooperativeKernel((const void*)all_kernel, dim3(nblk),
                                           dim3(256), args, 0, stream);
        }
    }
    if (e != hipSuccess) {
        (void)hipGetLastError();               // clear sticky error
        // R14 fallback (proven 171.4 us)
        conv_kernel<<<T / 2, 256, 0, stream>>>(w, w16);
        init_kernel<<<NPROP * T / 256, 256, 0, stream>>>(in, s0, y);
        sym_kernel<<<rowstart(IN / TILE), 256, 0, stream>>>(w16, s0, nullptr,
                                                            nullptr, y, 1);
        for (int it = 1; it < NPROP - 1; ++it)
            sym_kernel<<<NTILES, 256, 0, stream>>>(w16, nullptr,
                                                   y + (it - 1) * T, bv,
                                                   y + it * T, 0);
        sym_kernel<<<NTILES, 256, 0, stream>>>(w16, nullptr,
                                               y + (NPROP - 2) * T, bv,
                                               y + (NPROP - 1) * T, 2);
        actout_kernel<<<OUT / 256, 256, 0, stream>>>(bv, y + (NPROP - 1) * T,
                                                     out);
    }
}

// Round 20
// 165.284 us; speedup vs baseline: 6.3713x; 6.3713x over previous
//
#include <hip/hip_runtime.h>
#include <hip/hip_fp16.h>

// Symmetric pair-weight recurrent net, T=8192, 8 steps of s = tanh(M s + b).
// M symmetric, zero diagonal; stored ONLY as strict upper triangle in fp16.
// Layout v2: row starts padded to 64-half (128B) boundaries so conv's vector
// stores write COMPLETE cache lines (no partial-line RMW):
//   slot(r,j) = crow64(r) + j  (j > r), crow64(r) % 64 == 0.
// conv: row-wise contiguous streaming; head (<64 elems to the 64-boundary)
// elementwise, then 8-thread groups write full 128B lines.
// sym (R14 body): each pair weight read ONCE per pass, both directions
// accumulated; state staged as tanh(y_prev+b) on the fly.

constexpr int T     = 8192;
constexpr int IN    = 2048;
constexpr int OUT   = 1024;
constexpr int NPROP = 8;

constexpr int TILE   = 128;
constexpr int NT     = T / TILE;              // 64
constexpr int NTILES = NT * (NT + 1) / 2;     // 2080

// f32 source triangle index (j > r)
__device__ __forceinline__ unsigned triidx(unsigned r, unsigned j) {
    return r * (unsigned)(T - 1) - ((r * (r - 1u)) >> 1) + j - r - 1u;
}

// fp16 padded-triangle row base (halves), 128B-aligned:
//   crow64(r) = r*T - 64*S(r),  S(r) = sum_{k=1..r} floor(k/64)
//             = 32*a*(a-1) + a*(b+1)  with a = r>>6, b = r&63.
// Row r's valid slots: [crow64(r) + r + 1, crow64(r) + T); vector region
// starts at 64-half boundary. Write set injective across rows; sub-/on-
// diagonal slots alias other rows (read-only + masked in sym, NEVER stored).
__device__ __forceinline__ int crow64(int r) {
    int a = r >> 6, b = r & 63;
    return r * T - 64 * (32 * a * (a - 1) + a * (b + 1));
}
constexpr size_t W16_ALLOC = 33816576;   // crow64(8191)+8192; %8==0

__host__ __device__ __forceinline__ unsigned rowstart(int b) {
    return (unsigned)(b * NT) - (unsigned)((b * (b - 1)) >> 1);
}

__device__ __forceinline__ void tile_decode(unsigned p, int& bi, int& bj) {
    const float A = (float)(2 * NT + 1);      // 129
    bi = (int)((A - sqrtf(A * A - 8.0f * (float)p)) * 0.5f);
    if (bi < 0) bi = 0;
    while (rowstart(bi + 1) <= p) ++bi;
    while (rowstart(bi) > p) --bi;
    bj = bi + (int)(p - rowstart(bi));
}

__device__ __forceinline__ uint4 pack8(const float* v) {
    uint4 pk;
    ushort* us = (ushort*)&pk;
    #pragma unroll
    for (int d = 0; d < 8; ++d) us[d] = __half_as_ushort(__float2half_rn(v[d]));
    return pk;
}

__device__ __forceinline__ void sel8(float4 fA, float4 fB, float4 fC, int sel,
                                     float* v) {
    if (sel == 0) {
        v[0]=fA.x; v[1]=fA.y; v[2]=fA.z; v[3]=fA.w;
        v[4]=fB.x; v[5]=fB.y; v[6]=fB.z; v[7]=fB.w;
    } else if (sel == 1) {
        v[0]=fA.y; v[1]=fA.z; v[2]=fA.w; v[3]=fB.x;
        v[4]=fB.y; v[5]=fB.z; v[6]=fB.w; v[7]=fC.x;
    } else if (sel == 2) {
        v[0]=fA.z; v[1]=fA.w; v[2]=fB.x; v[3]=fB.y;
        v[4]=fB.z; v[5]=fB.w; v[6]=fC.x; v[7]=fC.y;
    } else {
        v[0]=fA.w; v[1]=fB.x; v[2]=fB.y; v[3]=fB.z;
        v[4]=fB.w; v[5]=fC.x; v[6]=fC.y; v[7]=fC.z;
    }
}

// ---- one-time f32 triangle -> fp16 padded triangle, ROW-WISE streaming ----
// Block b handles rows b and 8191-b. Head (to the 64-half boundary)
// elementwise; then threads stride aligned 8-half chunks — every 8-thread
// group writes one complete 128B line (no partial-line RMW).
__global__ __launch_bounds__(256) void conv_kernel(const float* __restrict__ w,
                                                   __half* __restrict__ w16) {
    int t = threadIdx.x;
    #pragma unroll
    for (int q = 0; q < 2; ++q) {
        int r = (q == 0) ? (int)blockIdx.x : (T - 1 - (int)blockIdx.x);
        int j1 = r + 1;
        int jA = (j1 + 63) & ~63;               // first 128B-aligned chunk col
        unsigned offr = triidx((unsigned)r, (unsigned)j1);  // row start in w
        int cr = crow64(r);
        if (t < jA - j1)                        // head (<64 elems)
            w16[cr + j1 + t] = __float2half_rn(w[offr + (unsigned)t]);
        if (jA >= T) continue;
        unsigned baseA = offr + (unsigned)(jA - j1);        // triidx(r, jA)
        int sel = (int)(baseA & 3u);            // uniform per row
        for (int j8 = jA + t * 8; j8 + 8 <= T; j8 += 8 * 256) {
            unsigned a0 = (baseA + (unsigned)(j8 - jA)) & ~3u;
            float4 fA = *(const float4*)(w + a0);
            float4 fB = *(const float4*)(w + a0 + 4);
            float4 fC = *(const float4*)(w + a0 + 8);
            float v[8];
            sel8(fA, fB, fC, sel, v);
            *(uint4*)(w16 + (cr + j8)) = pack8(v);
        }
    }
}

// init: build s0 (raw initial state, no tanh) and zero the 8 y accumulators.
__global__ __launch_bounds__(256) void init_kernel(const float* __restrict__ in,
                                                   float* __restrict__ s0,
                                                   float* __restrict__ y) {
    int n = blockIdx.x * 256 + threadIdx.x;
    if (n < T) s0[n] = (n < IN) ? in[n] : 0.0f;
    if (n < NPROP * T) y[n] = 0.0f;
}

// ---- fused symmetric tile pass (R14 body) ----
// mode 0: full. mode 1: iter1 (grid 904, bi<16; row side live only bj<16).
// mode 2: iter8 (only y[7168..] live).
// State: sp ? sp[idx] : tanh(yprev[idx] + bv[idx]).
__global__ __launch_bounds__(256) void sym_kernel(const __half* __restrict__ w16,
                                                  const float* __restrict__ sp,
                                                  const float* __restrict__ yprev,
                                                  const float* __restrict__ bv,
                                                  float* __restrict__ y, int mode) {
    __shared__ float sIl[TILE], sJl[TILE];
    __shared__ float colpart[4][TILE];

    int bi, bj; tile_decode(blockIdx.x, bi, bj);
    if (mode == 2 && bj < (T - OUT) / TILE) return;    // iter8: only y[7168..]
    bool doRow = (mode == 0) ? true
               : (mode == 1) ? (bj < IN / TILE)
                             : (bi >= (T - OUT) / TILE);

    int i0 = bi * TILE, j0 = bj * TILE;
    int t = threadIdx.x;
    {
        int idx = (t < TILE) ? (i0 + t) : (j0 + (t - TILE));
        float sval = sp ? sp[idx] : tanhf(yprev[idx] + bv[idx]);
        if (t < TILE) sIl[t] = sval;
        else          sJl[t - TILE] = sval;
    }
    __syncthreads();

    int l = t & 63, wv = t >> 6;
    int g = l & 15, ro = l >> 4;
    int cbase = j0 + g * 8;

    float sjv[8];
    #pragma unroll
    for (int d = 0; d < 8; ++d) sjv[d] = sJl[g * 8 + d];
    float colacc[8] = {0.f, 0.f, 0.f, 0.f, 0.f, 0.f, 0.f, 0.f};

    #pragma unroll
    for (int k = 0; k < 8; ++k) {
        int rr = wv * 32 + k * 4 + ro;
        int r  = i0 + rr;
        // aligned uint4: crow64(r)%64==0, cbase%8==0. Sub-diagonal slots in
        // diag tiles read in-allocation garbage and are masked below.
        uint4 wq = *(const uint4*)(w16 + (crow64(r) + cbase));
        const __half2* h2 = (const __half2*)&wq;
        float2 f0 = __half22float2(h2[0]);
        float2 f1 = __half22float2(h2[1]);
        float2 f2 = __half22float2(h2[2]);
        float2 f3 = __half22float2(h2[3]);
        float wf[8] = {f0.x, f0.y, f1.x, f1.y, f2.x, f2.y, f3.x, f3.y};

        float si = sIl[rr];
        float rp = 0.0f;
        #pragma unroll
        for (int d = 0; d < 8; ++d) {
            float we = (cbase + d > r) ? wf[d] : 0.0f;   // strict upper only
            colacc[d] = fmaf(we, si, colacc[d]);
            rp        = fmaf(we, sjv[d], rp);
        }
        if (doRow) {
            rp += __shfl_xor(rp, 1, 64);
            rp += __shfl_xor(rp, 2, 64);
            rp += __shfl_xor(rp, 4, 64);
            rp += __shfl_xor(rp, 8, 64);
            if (g == 0) atomicAdd(&y[r], rp);
        }
    }

    #pragma unroll
    for (int d = 0; d < 8; ++d) {
        colacc[d] += __shfl_xor(colacc[d], 16, 64);
        colacc[d] += __shfl_xor(colacc[d], 32, 64);
    }
    if (l < 16) {
        #pragma unroll
        for (int d = 0; d < 8; ++d) colpart[wv][g * 8 + d] = colacc[d];
    }
    __syncthreads();
    if (t < TILE) {
        float c = colpart[0][t] + colpart[1][t] + colpart[2][t] + colpart[3][t];
        atomicAdd(&y[j0 + t], c);
    }
}

__global__ __launch_bounds__(256) void actout_kernel(const float* __restrict__ b,
                                                     const float* __restrict__ y,
                                                     float* __restrict__ o) {
    int n = blockIdx.x * 256 + threadIdx.x;
    if (n < OUT) o[n] = tanhf(y[T - OUT + n] + b[T - OUT + n]);
}

extern "C" void kernel_launch(void* const* d_in, const int* in_sizes, int n_in,
                              void* d_out, int out_size, void* d_ws, size_t ws_size,
                              hipStream_t stream) {
    const float* in = (const float*)d_in[0];   // inputs [2048]
    const float* w  = (const float*)d_in[1];   // w_flat [T*(T-1)/2] f32
    const float* b  = (const float*)d_in[2];   // b [8192] f32
    float* out = (float*)d_out;                // [1024] f32

    __half* w16 = (__half*)d_ws;                               // 67.63 MB
    float*  s0  = (float*)((char*)d_ws + W16_ALLOC * sizeof(__half));
    float*  y   = s0 + T;                      // 8 accumulators, y + it*T

    conv_kernel<<<T / 2, 256, 0, stream>>>(w, w16);
    init_kernel<<<NPROP * T / 256, 256, 0, stream>>>(in, s0, y);

    // iter 1: tiles bi<16 (contiguous p < 904); state = s0 (no tanh)
    sym_kernel<<<rowstart(IN / TILE), 256, 0, stream>>>(w16, s0, nullptr, nullptr,
                                                        y, 1);
    // iters 2..7: state = tanh(y[it-2] + b), accumulate into y[it-1]
    for (int it = 1; it < NPROP - 1; ++it) {
        sym_kernel<<<NTILES, 256, 0, stream>>>(w16, nullptr, y + (it - 1) * T, b,
                                               y + it * T, 0);
    }
    // iter 8: only outputs 7168.. needed
    sym_kernel<<<NTILES, 256, 0, stream>>>(w16, nullptr, y + (NPROP - 2) * T, b,
                                           y + (NPROP - 1) * T, 2);
    actout_kernel<<<OUT / 256, 256, 0, stream>>>(b, y + (NPROP - 1) * T, out);
}